// Round 11
// baseline (334.024 us; speedup 1.0000x reference)
//
#include <hip/hip_runtime.h>
#include <math.h>

typedef __bf16 bf16x8 __attribute__((ext_vector_type(8)));
typedef float f32x4 __attribute__((ext_vector_type(4)));
typedef unsigned short u16;
typedef unsigned short u16x4 __attribute__((ext_vector_type(4)));
typedef unsigned short u16x8 __attribute__((ext_vector_type(8)));
typedef unsigned int u32;

#define AS1 __attribute__((address_space(1)))
#define AS3 __attribute__((address_space(3)))

static __device__ __forceinline__ float bf2f(u16 u) {
  union { u32 i; float f; } v; v.i = ((u32)u) << 16; return v.f;
}
static __device__ __forceinline__ u16 f2bf(float f) {
  union { float f; u32 i; } v; v.f = f;
  u32 r = v.i + 0x7FFFu + ((v.i >> 16) & 1u);
  return (u16)(r >> 16);
}

// ---- one-shot fp32 -> bf16 convert (memory-bound, coalesced) ----
__global__ __launch_bounds__(256)
void f32_to_bf16(const float* __restrict__ src, u16* __restrict__ dst, int n4) {
  const int gid = blockIdx.x * 256 + threadIdx.x;
  if (gid >= n4) return;
  const float4 v = ((const float4*)src)[gid];
  u16x4 p = {f2bf(v.x), f2bf(v.y), f2bf(v.z), f2bf(v.w)};
  ((u16x4*)dst)[gid] = p;
}

// ---- GEMM 256x256, BK=64, 8 waves, counted-vmcnt 4-phase pipeline ----
// LDS: 2 buffers x {A,B} x 2 halves x 128x64 bf16 = 128 KB (1 block/CU).
// T2 swizzle: kslot ^= row&7 (pre-swizzled source, linear LDS dest).
// Per tile: p0 = vmcnt(0)+barrier (only drain; covered by full-tile prefetch
// distance), stage 4 half-tiles of t+1, 12 ds_reads, 16 MFMA; p1-3 = 4 reads
// + 16 MFMA + drain-free barrier. setprio(1) around MFMA clusters.
template <bool CF32>
__global__ __launch_bounds__(512, 1)
void gemm256(const u16* __restrict__ A, const u16* __restrict__ B,
             void* __restrict__ Cp, int M, int N, int K) {
  __shared__ __align__(16) u16 Asb[2][2][128 * 64];
  __shared__ __align__(16) u16 Bsb[2][2][128 * 64];
  const int tid = threadIdx.x;
  const int lane = tid & 63;
  const int wid = tid >> 6;            // 0..7
  const int wr = wid >> 2, wc = wid & 3;
  const int l15 = lane & 15, l4 = lane >> 4;
  const int m0 = blockIdx.y * 256, n0 = blockIdx.x * 256;
  const int hb = wc >> 1;

  // staging addressing: idx=i*512+tid -> row=idx>>3, kslot=(idx&7)^(row&7)
  int srow[2], skc[2];
#pragma unroll
  for (int i = 0; i < 2; ++i) {
    const int idx = i * 512 + tid;
    srow[i] = idx >> 3;
    skc[i] = ((idx & 7) ^ (srow[i] & 7)) * 8;
  }

  f32x4 acc[8][4];
  const f32x4 fzero = {0.f, 0.f, 0.f, 0.f};
#pragma unroll
  for (int i = 0; i < 8; ++i)
#pragma unroll
    for (int j = 0; j < 4; ++j) acc[i][j] = fzero;

  const int NT = K >> 6;
  // prologue: stage tile 0 into buffer 0
#pragma unroll
  for (int hh = 0; hh < 2; ++hh)
#pragma unroll
    for (int i = 0; i < 2; ++i) {
      __builtin_amdgcn_global_load_lds(
          (AS1 void*)(A + (size_t)(m0 + hh * 128 + srow[i]) * K + skc[i]),
          (AS3 void*)(&Asb[0][hh][(i * 512 + tid) * 8]), 16, 0, 0);
      __builtin_amdgcn_global_load_lds(
          (AS1 void*)(B + (size_t)(n0 + hh * 128 + srow[i]) * K + skc[i]),
          (AS3 void*)(&Bsb[0][hh][(i * 512 + tid) * 8]), 16, 0, 0);
    }

  for (int t = 0; t < NT; ++t) {
    const int cur = t & 1, nxt = cur ^ 1;
    const int ktn = (t + 1) << 6;
    const bool hn = (t + 1 < NT);
    bf16x8 bfr[4][2];
#pragma unroll
    for (int p = 0; p < 4; ++p) {
      if (p == 0) {
        // the ONE drain per tile: own tile-t loads landed; barrier makes all
        // threads' loads visible; sched_barrier pins against motion.
        asm volatile("s_waitcnt vmcnt(0)" ::: "memory");
        __builtin_amdgcn_s_barrier();
        __builtin_amdgcn_sched_barrier(0);
        if (hn) {  // stage ALL of tile t+1 now -> full-tile latency cover
#pragma unroll
          for (int hh = 0; hh < 2; ++hh)
#pragma unroll
            for (int i = 0; i < 2; ++i) {
              __builtin_amdgcn_global_load_lds(
                  (AS1 void*)(A + (size_t)(m0 + hh * 128 + srow[i]) * K + ktn + skc[i]),
                  (AS3 void*)(&Asb[nxt][hh][(i * 512 + tid) * 8]), 16, 0, 0);
              __builtin_amdgcn_global_load_lds(
                  (AS1 void*)(B + (size_t)(n0 + hh * 128 + srow[i]) * K + ktn + skc[i]),
                  (AS3 void*)(&Bsb[nxt][hh][(i * 512 + tid) * 8]), 16, 0, 0);
            }
        }
        // all 8 B-frags for this tile
#pragma unroll
        for (int n = 0; n < 4; ++n)
#pragma unroll
          for (int ks = 0; ks < 2; ++ks) {
            const int rb = (wc & 1) * 64 + n * 16 + l15;
            const int kk = ((ks * 4 + l4) ^ (rb & 7)) * 8;
            bfr[n][ks] = *(const bf16x8*)&Bsb[cur][hb][rb * 64 + kk];
          }
      }
      // A-frags for quadrant p (m-frags 2p, 2p+1)
      bf16x8 af[2][2];
#pragma unroll
      for (int mm = 0; mm < 2; ++mm)
#pragma unroll
        for (int ks = 0; ks < 2; ++ks) {
          const int ra = (p * 2 + mm) * 16 + l15;
          const int kk = ((ks * 4 + l4) ^ (ra & 7)) * 8;
          af[mm][ks] = *(const bf16x8*)&Asb[cur][wr][ra * 64 + kk];
        }
      __builtin_amdgcn_s_setprio(1);
#pragma unroll
      for (int mm = 0; mm < 2; ++mm) {
        const int mi = p * 2 + mm;
#pragma unroll
        for (int n = 0; n < 4; ++n) {
          acc[mi][n] = __builtin_amdgcn_mfma_f32_16x16x32_bf16(af[mm][0], bfr[n][0], acc[mi][n], 0, 0, 0);
          acc[mi][n] = __builtin_amdgcn_mfma_f32_16x16x32_bf16(af[mm][1], bfr[n][1], acc[mi][n], 0, 0, 0);
        }
      }
      __builtin_amdgcn_s_setprio(0);
      if (p < 3) {  // drain-free phase lock
        __builtin_amdgcn_s_barrier();
        __builtin_amdgcn_sched_barrier(0);
      }
    }
  }

  // C-write: row=(lane>>4)*4+r, col=lane&15 per fragment
#pragma unroll
  for (int mi = 0; mi < 8; ++mi)
#pragma unroll
    for (int r = 0; r < 4; ++r) {
      const int gm = m0 + wr * 128 + mi * 16 + l4 * 4 + r;
      if constexpr (CF32) {
        float* crow = (float*)Cp + (size_t)gm * N + n0 + wc * 64 + l15;
#pragma unroll
        for (int n = 0; n < 4; ++n) crow[n * 16] = acc[mi][n][r];
      } else {
        u16* crow = (u16*)Cp + (size_t)gm * N + n0 + wc * 64 + l15;
#pragma unroll
        for (int n = 0; n < 4; ++n) crow[n * 16] = f2bf(acc[mi][n][r]);
      }
    }
}

// ---- GEMM 128x128 (m97 structure) — used for the small output projection ----
template <bool CF32>
__global__ __launch_bounds__(256, 2)
void gemm_bt(const u16* __restrict__ A, const u16* __restrict__ B,
             void* __restrict__ Cp, int M, int N, int K) {
  __shared__ __align__(16) u16 As[128 * 32];
  __shared__ __align__(16) u16 Bs[128 * 32];
  const int tid = threadIdx.x;
  const int lane = tid & 63;
  const int wid = tid >> 6;
  const int wr = wid >> 1, wc = wid & 1;
  const int l15 = lane & 15, l4 = lane >> 4;
  const int m0 = blockIdx.y * 128, n0 = blockIdx.x * 128;

  const f32x4 fzero = {0.f, 0.f, 0.f, 0.f};
  f32x4 acc[4][4];
#pragma unroll
  for (int i = 0; i < 4; ++i)
#pragma unroll
    for (int j = 0; j < 4; ++j) acc[i][j] = fzero;

  for (int kt = 0; kt < K; kt += 32) {
#pragma unroll
    for (int i = 0; i < 2; ++i) {
      const int c = wid * 64 + i * 256 + lane;
      const u16* ga = A + (size_t)(m0 + (c >> 2)) * K + kt + (c & 3) * 8;
      const u16* gb = B + (size_t)(n0 + (c >> 2)) * K + kt + (c & 3) * 8;
      __builtin_amdgcn_global_load_lds((AS1 void*)ga,
          (AS3 void*)(As + (size_t)(wid * 64 + i * 256) * 8), 16, 0, 0);
      __builtin_amdgcn_global_load_lds((AS1 void*)gb,
          (AS3 void*)(Bs + (size_t)(wid * 64 + i * 256) * 8), 16, 0, 0);
    }
    __syncthreads();
    bf16x8 af[4], bfr[4];
#pragma unroll
    for (int m = 0; m < 4; ++m)
      af[m] = *(const bf16x8*)&As[(wr * 64 + m * 16 + l15) * 32 + l4 * 8];
#pragma unroll
    for (int n = 0; n < 4; ++n)
      bfr[n] = *(const bf16x8*)&Bs[(wc * 64 + n * 16 + l15) * 32 + l4 * 8];
#pragma unroll
    for (int m = 0; m < 4; ++m)
#pragma unroll
      for (int n = 0; n < 4; ++n)
        acc[m][n] = __builtin_amdgcn_mfma_f32_16x16x32_bf16(af[m], bfr[n], acc[m][n], 0, 0, 0);
    __syncthreads();
  }

#pragma unroll
  for (int m = 0; m < 4; ++m)
#pragma unroll
    for (int r = 0; r < 4; ++r) {
      const int gm = m0 + wr * 64 + m * 16 + l4 * 4 + r;
      if constexpr (CF32) {
        float* crow = (float*)Cp + (size_t)gm * N + n0 + wc * 64 + l15;
#pragma unroll
        for (int n = 0; n < 4; ++n) crow[n * 16] = acc[m][n][r];
      } else {
        u16* crow = (u16*)Cp + (size_t)gm * N + n0 + wc * 64 + l15;
#pragma unroll
        for (int n = 0; n < 4; ++n) crow[n * 16] = f2bf(acc[m][n][r]);
      }
    }
}

// ---- RoPE in-place on q,k slots of qkv [B=2][T=2048][3][H=16][Dh=128] ----
__global__ __launch_bounds__(256)
void rope_kernel(u16* __restrict__ qkv, const int* __restrict__ seq_off) {
  const int idx = blockIdx.x * 256 + threadIdx.x;  // 4194304 threads
  const int d = idx & 63;
  const int h = (idx >> 6) & 15;
  const int t = (idx >> 10) & 2047;
  const int b = idx >> 21;
  const float pos = (float)(seq_off[0] + t);
  const float inv = expf((float)d * (-0.14391156509731588f));  // -ln(1e4)/64
  float sv, cv;
  sincosf(pos * inv, &sv, &cv);
  const size_t base = ((size_t)(b * 2048 + t)) * 6144 + h * 128 + d;
  const float q1 = bf2f(qkv[base]);
  const float q2 = bf2f(qkv[base + 64]);
  qkv[base] = f2bf(q1 * cv - q2 * sv);
  qkv[base + 64] = f2bf(q2 * cv + q1 * sv);
  const float k1 = bf2f(qkv[base + 2048]);
  const float k2 = bf2f(qkv[base + 2048 + 64]);
  qkv[base + 2048] = f2bf(k1 * cv - k2 * sv);
  qkv[base + 2048 + 64] = f2bf(k2 * cv + k1 * sv);
}

// ---- Flash attention v3 (round-10, unchanged) ----
__global__ __launch_bounds__(256, 2)
void attn_kernel(const u16* __restrict__ qkv, u16* __restrict__ ctx) {
  __shared__ __align__(16) u16 kbuf[2][32 * 128];
  __shared__ __align__(16) u16 vbuf[2][128 * 32];
  __shared__ __align__(16) u16 Plds[4][16 * 32];
  const int tid = threadIdx.x, lane = tid & 63, w = tid >> 6;
  const int l15 = lane & 15, l4 = lane >> 4;
  const int bh = blockIdx.y;
  const int b = bh >> 4, h = bh & 15;
  const u16* Qb = qkv + (size_t)b * 2048 * 6144 + h * 128;
  const u16* Kb = Qb + 2048;
  const u16* Vb = Qb + 4096;

  const int sp = tid & 15;
  const int sB = tid >> 4;
  const int sgp = sB & 1;
  const int swg = (((sp >> 2) ^ (sB & 3)) << 3) + ((sp & 3) << 1);
  const int ks0 = (w * 2 + 0) * 64 + lane;
  const int ks1 = (w * 2 + 1) * 64 + lane;
  const int kr0 = ks0 >> 4, kc0 = (ks0 & 15) ^ (kr0 & 15);
  const int kr1 = ks1 >> 4, kc1 = (ks1 & 15) ^ (kr1 & 15);

  const float scale = 0.08838834764831845f;
  const float M0 = 12.0f;
  const f32x4 fzero = {0.f, 0.f, 0.f, 0.f};

  for (int pass = 0; pass < 2; ++pass) {
    const int qt = pass ? (int)blockIdx.x : (31 - (int)blockIdx.x);
    const int q0 = qt * 64 + w * 16;
    const int nt_blk = qt * 2 + 2;

    bf16x8 qf[4];
#pragma unroll
    for (int c = 0; c < 4; ++c)
      qf[c] = *(const bf16x8*)(Qb + (size_t)(q0 + l15) * 6144 + c * 32 + l4 * 8);

    f32x4 o[8];
#pragma unroll
    for (int ch = 0; ch < 8; ++ch) o[ch] = fzero;
    float lpart[4] = {0.f, 0.f, 0.f, 0.f};

    __syncthreads();
    __builtin_amdgcn_global_load_lds((AS1 void*)(Kb + (size_t)kr0 * 6144 + kc0 * 8),
        (AS3 void*)(&kbuf[0][(w * 2 + 0) * 512]), 16, 0, 0);
    __builtin_amdgcn_global_load_lds((AS1 void*)(Kb + (size_t)kr1 * 6144 + kc1 * 8),
        (AS3 void*)(&kbuf[0][(w * 2 + 1) * 512]), 16, 0, 0);
    {
      const u16* vp = Vb + (size_t)(2 * sp) * 6144 + 8 * sB;
      const u16x8 v0 = *(const u16x8*)vp;
      const u16x8 v1 = *(const u16x8*)(vp + 6144);
#pragma unroll
      for (int e = 0; e < 8; ++e) {
        const int s = e ^ sgp;
        const int dh = 8 * sB + s;
        *(u32*)&vbuf[0][dh * 32 + swg] = (u32)v0[s] | ((u32)v1[s] << 16);
      }
    }
    __syncthreads();

    for (int t = 0; t < nt_blk; ++t) {
      const int cur = t & 1, nxtb = cur ^ 1;
      const int kv0 = t * 32;
      const bool has_next = (t + 1 < nt_blk);
      u16x8 v0, v1;
      if (has_next) {
        const u16* vp = Vb + (size_t)(kv0 + 32 + 2 * sp) * 6144 + 8 * sB;
        v0 = *(const u16x8*)vp;
        v1 = *(const u16x8*)(vp + 6144);
      }
      f32x4 s0 = fzero, s1 = fzero;
#pragma unroll
      for (int c = 0; c < 4; ++c) {
        const bf16x8 kf = *(const bf16x8*)&kbuf[cur][l15 * 128 + (((c * 4 + l4) ^ l15) << 3)];
        s0 = __builtin_amdgcn_mfma_f32_16x16x32_bf16(qf[c], kf, s0, 0, 0, 0);
      }
#pragma unroll
      for (int c = 0; c < 4; ++c) {
        const bf16x8 kf = *(const bf16x8*)&kbuf[cur][(16 + l15) * 128 + (((c * 4 + l4) ^ l15) << 3)];
        s1 = __builtin_amdgcn_mfma_f32_16x16x32_bf16(qf[c], kf, s1, 0, 0, 0);
      }
#pragma unroll
      for (int r = 0; r < 4; ++r) {
        const int qg = q0 + l4 * 4 + r;
        const float p0 = (kv0 + l15 <= qg) ? __expf(fmaf(s0[r], scale, -M0)) : 0.f;
        const float p1 = (kv0 + 16 + l15 <= qg) ? __expf(fmaf(s1[r], scale, -M0)) : 0.f;
        lpart[r] += p0 + p1;
        const int row = l4 * 4 + r;
        const int g0 = ((l15 >> 3) ^ l4) & 3;
        const int g1 = (((l15 >> 3) | 2) ^ l4) & 3;
        Plds[w][row * 32 + g0 * 8 + (l15 & 7)] = f2bf(p0);
        Plds[w][row * 32 + g1 * 8 + (l15 & 7)] = f2bf(p1);
      }
      __syncthreads();
      if (has_next) {
        __builtin_amdgcn_global_load_lds((AS1 void*)(Kb + (size_t)(kv0 + 32 + kr0) * 6144 + kc0 * 8),
            (AS3 void*)(&kbuf[nxtb][(w * 2 + 0) * 512]), 16, 0, 0);
        __builtin_amdgcn_global_load_lds((AS1 void*)(Kb + (size_t)(kv0 + 32 + kr1) * 6144 + kc1 * 8),
            (AS3 void*)(&kbuf[nxtb][(w * 2 + 1) * 512]), 16, 0, 0);
      }
      const bf16x8 pa = *(const bf16x8*)&Plds[w][l15 * 32 + ((l4 ^ (l15 >> 2)) << 3)];
#pragma unroll
      for (int ch = 0; ch < 8; ++ch) {
        const int dh = ch * 16 + l15;
        const int g = (l4 ^ ((2 * ch + (l15 >> 3)) & 3)) << 3;
        const bf16x8 vbf = *(const bf16x8*)&vbuf[cur][dh * 32 + g];
        o[ch] = __builtin_amdgcn_mfma_f32_16x16x32_bf16(pa, vbf, o[ch], 0, 0, 0);
      }
      if (has_next) {
#pragma unroll
        for (int e = 0; e < 8; ++e) {
          const int s = e ^ sgp;
          const int dh = 8 * sB + s;
          *(u32*)&vbuf[nxtb][dh * 32 + swg] = (u32)v0[s] | ((u32)v1[s] << 16);
        }
      }
    }
    float invl[4];
#pragma unroll
    for (int r = 0; r < 4; ++r) {
      float l = lpart[r];
      l += __shfl_xor(l, 1);
      l += __shfl_xor(l, 2);
      l += __shfl_xor(l, 4);
      l += __shfl_xor(l, 8);
      invl[r] = 1.0f / l;
    }
#pragma unroll
    for (int ch = 0; ch < 8; ++ch)
#pragma unroll
      for (int r = 0; r < 4; ++r) {
        const int gq = q0 + l4 * 4 + r;
        ctx[(size_t)(b * 2048 + gq) * 2048 + h * 128 + ch * 16 + l15] =
            f2bf(o[ch][r] * invl[r]);
      }
  }
}

extern "C" void kernel_launch(void* const* d_in, const int* in_sizes, int n_in,
                              void* d_out, int out_size, void* d_ws, size_t ws_size,
                              hipStream_t stream) {
  const float* x     = (const float*)d_in[0];   // (2,2048,2048) fp32
  const float* wqkv  = (const float*)d_in[1];   // (6144,2048) fp32
  const float* wproj = (const float*)d_in[2];   // (2048,2048) fp32
  const int*   soff  = (const int*)d_in[3];     // scalar int
  float* out = (float*)d_out;                   // (2,2048,2048) fp32

  u16* wsu    = (u16*)d_ws;
  u16* xb     = wsu;                    //  8388608 u16 (dead after gemm1)
  u16* wqkvb  = xb + 8388608;           // 12582912 u16
  u16* wprojb = wqkvb + 12582912;       //  4194304 u16
  u16* qkv    = wprojb + 4194304;       // 25165824 u16
  u16* ctx    = xb;                     // reuse xb region

  f32_to_bf16<<<8192, 256, 0, stream>>>(x, xb, 2097152);
  f32_to_bf16<<<12288, 256, 0, stream>>>(wqkv, wqkvb, 3145728);
  f32_to_bf16<<<4096, 256, 0, stream>>>(wproj, wprojb, 1048576);

  gemm256<false><<<dim3(24, 16), 512, 0, stream>>>(xb, wqkvb, qkv, 4096, 6144, 2048);
  rope_kernel<<<16384, 256, 0, stream>>>(qkv, soff);
  attn_kernel<<<dim3(16, 32), 256, 0, stream>>>(qkv, ctx);
  gemm_bt<true><<<dim3(16, 32), 256, 0, stream>>>(ctx, wprojb, out, 4096, 2048, 2048);
}

// Round 12
// 325.167 us; speedup vs baseline: 1.0272x; 1.0272x over previous
//
#include <hip/hip_runtime.h>
#include <math.h>

typedef __bf16 bf16x8 __attribute__((ext_vector_type(8)));
typedef float f32x4 __attribute__((ext_vector_type(4)));
typedef unsigned short u16;
typedef unsigned short u16x4 __attribute__((ext_vector_type(4)));
typedef unsigned short u16x8 __attribute__((ext_vector_type(8)));
typedef unsigned int u32;

#define AS1 __attribute__((address_space(1)))
#define AS3 __attribute__((address_space(3)))

static __device__ __forceinline__ float bf2f(u16 u) {
  union { u32 i; float f; } v; v.i = ((u32)u) << 16; return v.f;
}
static __device__ __forceinline__ u16 f2bf(float f) {
  union { float f; u32 i; } v; v.f = f;
  u32 r = v.i + 0x7FFFu + ((v.i >> 16) & 1u);
  return (u16)(r >> 16);
}

// ---- one-shot fp32 -> bf16 convert (memory-bound, coalesced) ----
__global__ __launch_bounds__(256)
void f32_to_bf16(const float* __restrict__ src, u16* __restrict__ dst, int n4) {
  const int gid = blockIdx.x * 256 + threadIdx.x;
  if (gid >= n4) return;
  const float4 v = ((const float4*)src)[gid];
  u16x4 p = {f2bf(v.x), f2bf(v.y), f2bf(v.z), f2bf(v.w)};
  ((u16x4*)dst)[gid] = p;
}

// ---- GEMM1: 256x128 tile, BK=64, 8 waves, dbuf, ONE barrier/K-tile ----
// grid (N/128, M/256) = 48x16 = 768 blocks = exactly 3 dispatch waves (no tail).
// 2-phase recipe (m248): STAGE(t+1,nxt) -> ds_read(cur) -> MFMA -> barrier.
// T2 swizzle: kslot ^= row&7 on stage source; matched XOR on reads.
template <bool CF32>
__global__ __launch_bounds__(512, 1)
void gemm_bt2(const u16* __restrict__ A, const u16* __restrict__ B,
              void* __restrict__ Cp, int M, int N, int K) {
  __shared__ __align__(16) u16 As2[2][256 * 64];   // 64 KB
  __shared__ __align__(16) u16 Bs2[2][128 * 64];   // 32 KB
  const int tid = threadIdx.x;
  const int lane = tid & 63;
  const int wid = tid >> 6;            // 0..7
  const int wr = wid >> 2, wc = wid & 3;
  const int l15 = lane & 15, l4 = lane >> 4;
  const int m0 = blockIdx.y * 256, n0 = blockIdx.x * 128;

  // staging maps (proven in r11): idx -> row=idx>>3, kslot=(idx&7)^(row&7)
  int arow[4], akc[4];
#pragma unroll
  for (int i = 0; i < 4; ++i) {
    const int idx = i * 512 + tid;
    arow[i] = idx >> 3;
    akc[i] = ((idx & 7) ^ (arow[i] & 7)) * 8;
  }
  int brow[2], bkc[2];
#pragma unroll
  for (int i = 0; i < 2; ++i) {
    const int idx = i * 512 + tid;
    brow[i] = idx >> 3;
    bkc[i] = ((idx & 7) ^ (brow[i] & 7)) * 8;
  }

  f32x4 acc[8][2];
  const f32x4 fzero = {0.f, 0.f, 0.f, 0.f};
#pragma unroll
  for (int i = 0; i < 8; ++i) {
    acc[i][0] = fzero; acc[i][1] = fzero;
  }

  const int NT = K >> 6;
  // prologue: stage tile 0 into buf 0
#pragma unroll
  for (int i = 0; i < 4; ++i)
    __builtin_amdgcn_global_load_lds(
        (AS1 void*)(A + (size_t)(m0 + arow[i]) * K + akc[i]),
        (AS3 void*)(&As2[0][(i * 512 + tid) * 8]), 16, 0, 0);
#pragma unroll
  for (int i = 0; i < 2; ++i)
    __builtin_amdgcn_global_load_lds(
        (AS1 void*)(B + (size_t)(n0 + brow[i]) * K + bkc[i]),
        (AS3 void*)(&Bs2[0][(i * 512 + tid) * 8]), 16, 0, 0);
  __syncthreads();

  for (int t = 0; t < NT; ++t) {
    const int cur = t & 1, nxt = cur ^ 1;
    if (t + 1 < NT) {  // stage-early: issue t+1 loads before compute of t
      const int ktn = (t + 1) << 6;
#pragma unroll
      for (int i = 0; i < 4; ++i)
        __builtin_amdgcn_global_load_lds(
            (AS1 void*)(A + (size_t)(m0 + arow[i]) * K + ktn + akc[i]),
            (AS3 void*)(&As2[nxt][(i * 512 + tid) * 8]), 16, 0, 0);
#pragma unroll
      for (int i = 0; i < 2; ++i)
        __builtin_amdgcn_global_load_lds(
            (AS1 void*)(B + (size_t)(n0 + brow[i]) * K + ktn + bkc[i]),
            (AS3 void*)(&Bs2[nxt][(i * 512 + tid) * 8]), 16, 0, 0);
    }
    // read all fragments of tile t
    bf16x8 af[8][2], bfr[2][2];
#pragma unroll
    for (int n = 0; n < 2; ++n)
#pragma unroll
      for (int ks = 0; ks < 2; ++ks) {
        const int rb = wc * 32 + n * 16 + l15;
        const int kk = ((ks * 4 + l4) ^ (rb & 7)) * 8;
        bfr[n][ks] = *(const bf16x8*)&Bs2[cur][rb * 64 + kk];
      }
#pragma unroll
    for (int mi = 0; mi < 8; ++mi)
#pragma unroll
      for (int ks = 0; ks < 2; ++ks) {
        const int ra = wr * 128 + mi * 16 + l15;
        const int kk = ((ks * 4 + l4) ^ (ra & 7)) * 8;
        af[mi][ks] = *(const bf16x8*)&As2[cur][ra * 64 + kk];
      }
    __builtin_amdgcn_s_setprio(1);
#pragma unroll
    for (int mi = 0; mi < 8; ++mi)
#pragma unroll
      for (int n = 0; n < 2; ++n) {
        acc[mi][n] = __builtin_amdgcn_mfma_f32_16x16x32_bf16(af[mi][0], bfr[n][0], acc[mi][n], 0, 0, 0);
        acc[mi][n] = __builtin_amdgcn_mfma_f32_16x16x32_bf16(af[mi][1], bfr[n][1], acc[mi][n], 0, 0, 0);
      }
    __builtin_amdgcn_s_setprio(0);
    __syncthreads();  // the ONE barrier: drains t+1 stages, fences buffer swap
  }

  // C-write: row=(lane>>4)*4+r, col=lane&15 per fragment
#pragma unroll
  for (int mi = 0; mi < 8; ++mi)
#pragma unroll
    for (int r = 0; r < 4; ++r) {
      const int gm = m0 + wr * 128 + mi * 16 + l4 * 4 + r;
      if constexpr (CF32) {
        float* crow = (float*)Cp + (size_t)gm * N + n0 + wc * 32 + l15;
#pragma unroll
        for (int n = 0; n < 2; ++n) crow[n * 16] = acc[mi][n][r];
      } else {
        u16* crow = (u16*)Cp + (size_t)gm * N + n0 + wc * 32 + l15;
#pragma unroll
        for (int n = 0; n < 2; ++n) crow[n * 16] = f2bf(acc[mi][n][r]);
      }
    }
}

// ---- GEMM 128x128 (m97 structure) — output projection (512 blocks = 2 waves) ----
template <bool CF32>
__global__ __launch_bounds__(256, 2)
void gemm_bt(const u16* __restrict__ A, const u16* __restrict__ B,
             void* __restrict__ Cp, int M, int N, int K) {
  __shared__ __align__(16) u16 As[128 * 32];
  __shared__ __align__(16) u16 Bs[128 * 32];
  const int tid = threadIdx.x;
  const int lane = tid & 63;
  const int wid = tid >> 6;
  const int wr = wid >> 1, wc = wid & 1;
  const int l15 = lane & 15, l4 = lane >> 4;
  const int m0 = blockIdx.y * 128, n0 = blockIdx.x * 128;

  const f32x4 fzero = {0.f, 0.f, 0.f, 0.f};
  f32x4 acc[4][4];
#pragma unroll
  for (int i = 0; i < 4; ++i)
#pragma unroll
    for (int j = 0; j < 4; ++j) acc[i][j] = fzero;

  for (int kt = 0; kt < K; kt += 32) {
#pragma unroll
    for (int i = 0; i < 2; ++i) {
      const int c = wid * 64 + i * 256 + lane;
      const u16* ga = A + (size_t)(m0 + (c >> 2)) * K + kt + (c & 3) * 8;
      const u16* gb = B + (size_t)(n0 + (c >> 2)) * K + kt + (c & 3) * 8;
      __builtin_amdgcn_global_load_lds((AS1 void*)ga,
          (AS3 void*)(As + (size_t)(wid * 64 + i * 256) * 8), 16, 0, 0);
      __builtin_amdgcn_global_load_lds((AS1 void*)gb,
          (AS3 void*)(Bs + (size_t)(wid * 64 + i * 256) * 8), 16, 0, 0);
    }
    __syncthreads();
    bf16x8 af[4], bfr[4];
#pragma unroll
    for (int m = 0; m < 4; ++m)
      af[m] = *(const bf16x8*)&As[(wr * 64 + m * 16 + l15) * 32 + l4 * 8];
#pragma unroll
    for (int n = 0; n < 4; ++n)
      bfr[n] = *(const bf16x8*)&Bs[(wc * 64 + n * 16 + l15) * 32 + l4 * 8];
#pragma unroll
    for (int m = 0; m < 4; ++m)
#pragma unroll
      for (int n = 0; n < 4; ++n)
        acc[m][n] = __builtin_amdgcn_mfma_f32_16x16x32_bf16(af[m], bfr[n], acc[m][n], 0, 0, 0);
    __syncthreads();
  }

#pragma unroll
  for (int m = 0; m < 4; ++m)
#pragma unroll
    for (int r = 0; r < 4; ++r) {
      const int gm = m0 + wr * 64 + m * 16 + l4 * 4 + r;
      if constexpr (CF32) {
        float* crow = (float*)Cp + (size_t)gm * N + n0 + wc * 64 + l15;
#pragma unroll
        for (int n = 0; n < 4; ++n) crow[n * 16] = acc[m][n][r];
      } else {
        u16* crow = (u16*)Cp + (size_t)gm * N + n0 + wc * 64 + l15;
#pragma unroll
        for (int n = 0; n < 4; ++n) crow[n * 16] = f2bf(acc[m][n][r]);
      }
    }
}

// ---- RoPE in-place on q,k slots of qkv [B=2][T=2048][3][H=16][Dh=128] ----
__global__ __launch_bounds__(256)
void rope_kernel(u16* __restrict__ qkv, const int* __restrict__ seq_off) {
  const int idx = blockIdx.x * 256 + threadIdx.x;  // 4194304 threads
  const int d = idx & 63;
  const int h = (idx >> 6) & 15;
  const int t = (idx >> 10) & 2047;
  const int b = idx >> 21;
  const float pos = (float)(seq_off[0] + t);
  const float inv = expf((float)d * (-0.14391156509731588f));  // -ln(1e4)/64
  float sv, cv;
  sincosf(pos * inv, &sv, &cv);
  const size_t base = ((size_t)(b * 2048 + t)) * 6144 + h * 128 + d;
  const float q1 = bf2f(qkv[base]);
  const float q2 = bf2f(qkv[base + 64]);
  qkv[base] = f2bf(q1 * cv - q2 * sv);
  qkv[base + 64] = f2bf(q2 * cv + q1 * sv);
  const float k1 = bf2f(qkv[base + 2048]);
  const float k2 = bf2f(qkv[base + 2048 + 64]);
  qkv[base + 2048] = f2bf(k1 * cv - k2 * sv);
  qkv[base + 2048 + 64] = f2bf(k2 * cv + k1 * sv);
}

// ---- Flash attention v3 (round-10, unchanged) ----
__global__ __launch_bounds__(256, 2)
void attn_kernel(const u16* __restrict__ qkv, u16* __restrict__ ctx) {
  __shared__ __align__(16) u16 kbuf[2][32 * 128];
  __shared__ __align__(16) u16 vbuf[2][128 * 32];
  __shared__ __align__(16) u16 Plds[4][16 * 32];
  const int tid = threadIdx.x, lane = tid & 63, w = tid >> 6;
  const int l15 = lane & 15, l4 = lane >> 4;
  const int bh = blockIdx.y;
  const int b = bh >> 4, h = bh & 15;
  const u16* Qb = qkv + (size_t)b * 2048 * 6144 + h * 128;
  const u16* Kb = Qb + 2048;
  const u16* Vb = Qb + 4096;

  const int sp = tid & 15;
  const int sB = tid >> 4;
  const int sgp = sB & 1;
  const int swg = (((sp >> 2) ^ (sB & 3)) << 3) + ((sp & 3) << 1);
  const int ks0 = (w * 2 + 0) * 64 + lane;
  const int ks1 = (w * 2 + 1) * 64 + lane;
  const int kr0 = ks0 >> 4, kc0 = (ks0 & 15) ^ (kr0 & 15);
  const int kr1 = ks1 >> 4, kc1 = (ks1 & 15) ^ (kr1 & 15);

  const float scale = 0.08838834764831845f;
  const float M0 = 12.0f;
  const f32x4 fzero = {0.f, 0.f, 0.f, 0.f};

  for (int pass = 0; pass < 2; ++pass) {
    const int qt = pass ? (int)blockIdx.x : (31 - (int)blockIdx.x);
    const int q0 = qt * 64 + w * 16;
    const int nt_blk = qt * 2 + 2;

    bf16x8 qf[4];
#pragma unroll
    for (int c = 0; c < 4; ++c)
      qf[c] = *(const bf16x8*)(Qb + (size_t)(q0 + l15) * 6144 + c * 32 + l4 * 8);

    f32x4 o[8];
#pragma unroll
    for (int ch = 0; ch < 8; ++ch) o[ch] = fzero;
    float lpart[4] = {0.f, 0.f, 0.f, 0.f};

    __syncthreads();
    __builtin_amdgcn_global_load_lds((AS1 void*)(Kb + (size_t)kr0 * 6144 + kc0 * 8),
        (AS3 void*)(&kbuf[0][(w * 2 + 0) * 512]), 16, 0, 0);
    __builtin_amdgcn_global_load_lds((AS1 void*)(Kb + (size_t)kr1 * 6144 + kc1 * 8),
        (AS3 void*)(&kbuf[0][(w * 2 + 1) * 512]), 16, 0, 0);
    {
      const u16* vp = Vb + (size_t)(2 * sp) * 6144 + 8 * sB;
      const u16x8 v0 = *(const u16x8*)vp;
      const u16x8 v1 = *(const u16x8*)(vp + 6144);
#pragma unroll
      for (int e = 0; e < 8; ++e) {
        const int s = e ^ sgp;
        const int dh = 8 * sB + s;
        *(u32*)&vbuf[0][dh * 32 + swg] = (u32)v0[s] | ((u32)v1[s] << 16);
      }
    }
    __syncthreads();

    for (int t = 0; t < nt_blk; ++t) {
      const int cur = t & 1, nxtb = cur ^ 1;
      const int kv0 = t * 32;
      const bool has_next = (t + 1 < nt_blk);
      u16x8 v0, v1;
      if (has_next) {
        const u16* vp = Vb + (size_t)(kv0 + 32 + 2 * sp) * 6144 + 8 * sB;
        v0 = *(const u16x8*)vp;
        v1 = *(const u16x8*)(vp + 6144);
      }
      f32x4 s0 = fzero, s1 = fzero;
#pragma unroll
      for (int c = 0; c < 4; ++c) {
        const bf16x8 kf = *(const bf16x8*)&kbuf[cur][l15 * 128 + (((c * 4 + l4) ^ l15) << 3)];
        s0 = __builtin_amdgcn_mfma_f32_16x16x32_bf16(qf[c], kf, s0, 0, 0, 0);
      }
#pragma unroll
      for (int c = 0; c < 4; ++c) {
        const bf16x8 kf = *(const bf16x8*)&kbuf[cur][(16 + l15) * 128 + (((c * 4 + l4) ^ l15) << 3)];
        s1 = __builtin_amdgcn_mfma_f32_16x16x32_bf16(qf[c], kf, s1, 0, 0, 0);
      }
#pragma unroll
      for (int r = 0; r < 4; ++r) {
        const int qg = q0 + l4 * 4 + r;
        const float p0 = (kv0 + l15 <= qg) ? __expf(fmaf(s0[r], scale, -M0)) : 0.f;
        const float p1 = (kv0 + 16 + l15 <= qg) ? __expf(fmaf(s1[r], scale, -M0)) : 0.f;
        lpart[r] += p0 + p1;
        const int row = l4 * 4 + r;
        const int g0 = ((l15 >> 3) ^ l4) & 3;
        const int g1 = (((l15 >> 3) | 2) ^ l4) & 3;
        Plds[w][row * 32 + g0 * 8 + (l15 & 7)] = f2bf(p0);
        Plds[w][row * 32 + g1 * 8 + (l15 & 7)] = f2bf(p1);
      }
      __syncthreads();
      if (has_next) {
        __builtin_amdgcn_global_load_lds((AS1 void*)(Kb + (size_t)(kv0 + 32 + kr0) * 6144 + kc0 * 8),
            (AS3 void*)(&kbuf[nxtb][(w * 2 + 0) * 512]), 16, 0, 0);
        __builtin_amdgcn_global_load_lds((AS1 void*)(Kb + (size_t)(kv0 + 32 + kr1) * 6144 + kc1 * 8),
            (AS3 void*)(&kbuf[nxtb][(w * 2 + 1) * 512]), 16, 0, 0);
      }
      const bf16x8 pa = *(const bf16x8*)&Plds[w][l15 * 32 + ((l4 ^ (l15 >> 2)) << 3)];
#pragma unroll
      for (int ch = 0; ch < 8; ++ch) {
        const int dh = ch * 16 + l15;
        const int g = (l4 ^ ((2 * ch + (l15 >> 3)) & 3)) << 3;
        const bf16x8 vbf = *(const bf16x8*)&vbuf[cur][dh * 32 + g];
        o[ch] = __builtin_amdgcn_mfma_f32_16x16x32_bf16(pa, vbf, o[ch], 0, 0, 0);
      }
      if (has_next) {
#pragma unroll
        for (int e = 0; e < 8; ++e) {
          const int s = e ^ sgp;
          const int dh = 8 * sB + s;
          *(u32*)&vbuf[nxtb][dh * 32 + swg] = (u32)v0[s] | ((u32)v1[s] << 16);
        }
      }
    }
    float invl[4];
#pragma unroll
    for (int r = 0; r < 4; ++r) {
      float l = lpart[r];
      l += __shfl_xor(l, 1);
      l += __shfl_xor(l, 2);
      l += __shfl_xor(l, 4);
      l += __shfl_xor(l, 8);
      invl[r] = 1.0f / l;
    }
#pragma unroll
    for (int ch = 0; ch < 8; ++ch)
#pragma unroll
      for (int r = 0; r < 4; ++r) {
        const int gq = q0 + l4 * 4 + r;
        ctx[(size_t)(b * 2048 + gq) * 2048 + h * 128 + ch * 16 + l15] =
            f2bf(o[ch][r] * invl[r]);
      }
  }
}

extern "C" void kernel_launch(void* const* d_in, const int* in_sizes, int n_in,
                              void* d_out, int out_size, void* d_ws, size_t ws_size,
                              hipStream_t stream) {
  const float* x     = (const float*)d_in[0];   // (2,2048,2048) fp32
  const float* wqkv  = (const float*)d_in[1];   // (6144,2048) fp32
  const float* wproj = (const float*)d_in[2];   // (2048,2048) fp32
  const int*   soff  = (const int*)d_in[3];     // scalar int
  float* out = (float*)d_out;                   // (2,2048,2048) fp32

  u16* wsu    = (u16*)d_ws;
  u16* xb     = wsu;                    //  8388608 u16 (dead after gemm1)
  u16* wqkvb  = xb + 8388608;           // 12582912 u16
  u16* wprojb = wqkvb + 12582912;       //  4194304 u16
  u16* qkv    = wprojb + 4194304;       // 25165824 u16
  u16* ctx    = xb;                     // reuse xb region

  f32_to_bf16<<<8192, 256, 0, stream>>>(x, xb, 2097152);
  f32_to_bf16<<<12288, 256, 0, stream>>>(wqkv, wqkvb, 3145728);
  f32_to_bf16<<<4096, 256, 0, stream>>>(wproj, wprojb, 1048576);

  gemm_bt2<false><<<dim3(48, 16), 512, 0, stream>>>(xb, wqkvb, qkv, 4096, 6144, 2048);
  rope_kernel<<<16384, 256, 0, stream>>>(qkv, soff);
  attn_kernel<<<dim3(16, 32), 256, 0, stream>>>(qkv, ctx);
  gemm_bt<true><<<dim3(16, 32), 256, 0, stream>>>(ctx, wprojb, out, 4096, 2048, 2048);
}